// Round 1
// baseline (30246.298 us; speedup 1.0000x reference)
//
#include <hip/hip_runtime.h>
#include <math.h>

#define BATCH 131072
#define NSTEPS 256

__device__ __forceinline__ float fast_exp(float x) {
    return __builtin_amdgcn_exp2f(x * 1.44269504088896340736f);
}
__device__ __forceinline__ float fast_rcp(float x) {
    return __builtin_amdgcn_rcpf(x);
}
__device__ __forceinline__ float sigmoidf_fast(float x) {
    // 1/(1+exp(-x)); v_exp_f32 handles the full range (inf -> 0, 0 -> 1)
    return fast_rcp(1.0f + fast_exp(-x));
}

__global__ __launch_bounds__(256) void deep_hedging_kernel(
    const float* __restrict__ noise,   // (NSTEPS, BATCH)
    const float* __restrict__ ts,      // (NSTEPS+1)
    const float* __restrict__ w,       // scalar
    const float* __restrict__ W1,      // (32,2)
    const float* __restrict__ b1,      // (32)
    const float* __restrict__ W2,      // (32,32)
    const float* __restrict__ b2,      // (32)
    const float* __restrict__ W3,      // (1,32)
    const float* __restrict__ b3,      // (1)
    float* __restrict__ out)           // (BATCH)
{
    __shared__ float sW1[64];
    __shared__ float sb1[32];
    __shared__ float sW2[1024];
    __shared__ float sb2[32];
    __shared__ float sW3[32];
    __shared__ float sb3w[2];
    __shared__ float sts[NSTEPS + 1];

    const int tid = threadIdx.x;
    for (int i = tid; i < 1024; i += 256) sW2[i] = W2[i];
    if (tid < 64) sW1[tid] = W1[tid];
    if (tid < 32) { sb1[tid] = b1[tid]; sb2[tid] = b2[tid]; sW3[tid] = W3[tid]; }
    if (tid == 0) { sb3w[0] = b3[0]; sb3w[1] = w[0]; }
    for (int i = tid; i < NSTEPS + 1; i += 256) sts[i] = ts[i];
    __syncthreads();

    const int gid = blockIdx.x * 256 + tid;

    float s   = 1.0f;   // y[:,0]
    float pnl = 0.0f;   // y[:,1]
    const float b3v = sb3w[0];

    for (int st = 0; st < NSTEPS; ++st) {
        const float t  = sts[st];
        const float dt = sts[st + 1] - t;
        const float dW = noise[(size_t)st * BATCH + gid] * __builtin_sqrtf(dt);

        // ---- MLP forward + JVP tangent. input x=(t,s), tangent (0, sd), sd = SIGMA*s
        const float sd = s;  // SIGMA = 1
        float a1[32], t1[32];
        #pragma unroll
        for (int j = 0; j < 32; ++j) {
            const float w0 = sW1[2 * j];
            const float w1 = sW1[2 * j + 1];
            const float z  = fmaf(w0, t, fmaf(w1, s, sb1[j]));
            const float zd = w1 * sd;
            const float sg = sigmoidf_fast(z);
            const float da = sg * (1.0f + z * (1.0f - sg));  // silu'(z)
            a1[j] = z * sg;                                   // silu(z)
            t1[j] = da * zd;
        }

        float acc  = b3v;
        float accd = 0.0f;
        #pragma unroll
        for (int j = 0; j < 32; ++j) {
            float z  = sb2[j];
            float zd = 0.0f;
            #pragma unroll
            for (int i = 0; i < 32; ++i) {
                const float wv = sW2[j * 32 + i];
                z  = fmaf(wv, a1[i], z);
                zd = fmaf(wv, t1[i], zd);
            }
            const float sg = sigmoidf_fast(z);
            const float da = sg * (1.0f + z * (1.0f - sg));
            acc  = fmaf(sW3[j], z * sg, acc);
            accd = fmaf(sW3[j], da * zd, accd);
        }
        const float h  = sigmoidf_fast(acc);
        const float hd = h * (1.0f - h) * accd;   // tangent of h along JVP direction

        // Milstein update (MU = SIGMA = 1):
        // f=(s, s*h); g=(s, s*h); dg=(sd, sd*h + s*hd)
        const float mil = 0.5f * (dW * dW - dt);
        const float g1  = s * h;
        const float dg1 = fmaf(sd, h, s * hd);

        const float snew = s + s * dt + s * dW + sd * mil;
        pnl = pnl + g1 * dt + g1 * dW + dg1 * mil;
        s = snew;
    }

    const float z = fmaxf(0.0f, s - 3.0f);
    const float d = z - pnl - sb3w[1];
    out[gid] = d * d;
}

extern "C" void kernel_launch(void* const* d_in, const int* in_sizes, int n_in,
                              void* d_out, int out_size, void* d_ws, size_t ws_size,
                              hipStream_t stream) {
    const float* noise = (const float*)d_in[0];
    const float* ts    = (const float*)d_in[1];
    const float* w     = (const float*)d_in[2];
    const float* W1    = (const float*)d_in[3];
    const float* b1    = (const float*)d_in[4];
    const float* W2    = (const float*)d_in[5];
    const float* b2    = (const float*)d_in[6];
    const float* W3    = (const float*)d_in[7];
    const float* b3    = (const float*)d_in[8];
    float* out = (float*)d_out;

    dim3 grid(BATCH / 256), block(256);
    deep_hedging_kernel<<<grid, block, 0, stream>>>(noise, ts, w, W1, b1, W2, b2,
                                                    W3, b3, out);
}

// Round 2
// 9238.467 us; speedup vs baseline: 3.2740x; 3.2740x over previous
//
#include <hip/hip_runtime.h>
#include <math.h>

#define BATCH 131072
#define NSTEPS 256

__device__ __forceinline__ float fast_exp(float x) {
    return __builtin_amdgcn_exp2f(x * 1.44269504088896340736f);
}
__device__ __forceinline__ float fast_rcp(float x) {
    return __builtin_amdgcn_rcpf(x);
}
__device__ __forceinline__ float sigmoidf_fast(float x) {
    // 1/(1+exp(-x)); v_exp_f32 handles the full range (inf -> 0, 0 -> 1)
    return fast_rcp(1.0f + fast_exp(-x));
}

__global__ __launch_bounds__(256, 4) void deep_hedging_kernel(
    const float* __restrict__ noise,   // (NSTEPS, BATCH)
    const float* __restrict__ ts,      // (NSTEPS+1)
    const float* __restrict__ w,       // scalar
    const float* __restrict__ W1,      // (32,2)
    const float* __restrict__ b1,      // (32)
    const float* __restrict__ W2,      // (32,32)
    const float* __restrict__ b2,      // (32)
    const float* __restrict__ W3,      // (1,32)
    const float* __restrict__ b3,      // (1)
    float* __restrict__ out)           // (BATCH)
{
    __shared__ float sW1[64];
    __shared__ float sb1[32];
    __shared__ float sW2[1024];
    __shared__ float sb2[32];
    __shared__ float sW3[32];
    __shared__ float sb3w[2];
    __shared__ float sts[NSTEPS + 1];

    const int tid = threadIdx.x;
    for (int i = tid; i < 1024; i += 256) sW2[i] = W2[i];
    if (tid < 64) sW1[tid] = W1[tid];
    if (tid < 32) { sb1[tid] = b1[tid]; sb2[tid] = b2[tid]; sW3[tid] = W3[tid]; }
    if (tid == 0) { sb3w[0] = b3[0]; sb3w[1] = w[0]; }
    for (int i = tid; i < NSTEPS + 1; i += 256) sts[i] = ts[i];
    __syncthreads();

    const int gid = blockIdx.x * 256 + tid;
    const float* np_ = noise + gid;

    float s   = 1.0f;   // y[:,0]
    float pnl = 0.0f;   // y[:,1]
    const float b3v = sb3w[0];

    #pragma unroll 1
    for (int st = 0; st < NSTEPS; ++st) {
        const float t  = sts[st];
        const float dt = sts[st + 1] - t;
        const float dW = np_[(size_t)st * BATCH] * __builtin_sqrtf(dt);

        // ---- MLP forward + JVP tangent. input x=(t,s), tangent (0, sd), sd = SIGMA*s
        const float sd = s;  // SIGMA = 1
        float a1[32], t1[32];
        #pragma unroll 4
        for (int j = 0; j < 32; ++j) {
            const float w0 = sW1[2 * j];
            const float w1 = sW1[2 * j + 1];
            const float z  = fmaf(w0, t, fmaf(w1, s, sb1[j]));
            const float zd = w1 * sd;
            const float sg = sigmoidf_fast(z);
            const float da = sg * (1.0f + z * (1.0f - sg));  // silu'(z)
            a1[j] = z * sg;                                   // silu(z)
            t1[j] = da * zd;
        }

        float acc  = b3v;
        float accd = 0.0f;
        #pragma unroll 2
        for (int j = 0; j < 32; ++j) {
            float z  = sb2[j];
            float zd = 0.0f;
            #pragma unroll
            for (int i = 0; i < 32; ++i) {
                const float wv = sW2[j * 32 + i];
                z  = fmaf(wv, a1[i], z);
                zd = fmaf(wv, t1[i], zd);
            }
            const float sg = sigmoidf_fast(z);
            const float da = sg * (1.0f + z * (1.0f - sg));
            acc  = fmaf(sW3[j], z * sg, acc);
            accd = fmaf(sW3[j], da * zd, accd);
        }
        const float h  = sigmoidf_fast(acc);
        const float hd = h * (1.0f - h) * accd;   // tangent of h along JVP direction

        // Milstein update (MU = SIGMA = 1):
        // f=(s, s*h); g=(s, s*h); dg=(sd, sd*h + s*hd)
        const float mil = 0.5f * (dW * dW - dt);
        const float g1  = s * h;
        const float dg1 = fmaf(sd, h, s * hd);

        const float snew = s + s * dt + s * dW + sd * mil;
        pnl = pnl + g1 * dt + g1 * dW + dg1 * mil;
        s = snew;
    }

    const float z = fmaxf(0.0f, s - 3.0f);
    const float d = z - pnl - sb3w[1];
    out[gid] = d * d;
}

extern "C" void kernel_launch(void* const* d_in, const int* in_sizes, int n_in,
                              void* d_out, int out_size, void* d_ws, size_t ws_size,
                              hipStream_t stream) {
    const float* noise = (const float*)d_in[0];
    const float* ts    = (const float*)d_in[1];
    const float* w     = (const float*)d_in[2];
    const float* W1    = (const float*)d_in[3];
    const float* b1    = (const float*)d_in[4];
    const float* W2    = (const float*)d_in[5];
    const float* b2    = (const float*)d_in[6];
    const float* W3    = (const float*)d_in[7];
    const float* b3    = (const float*)d_in[8];
    float* out = (float*)d_out;

    dim3 grid(BATCH / 256), block(256);
    deep_hedging_kernel<<<grid, block, 0, stream>>>(noise, ts, w, W1, b1, W2, b2,
                                                    W3, b3, out);
}